// Round 1
// baseline (774.618 us; speedup 1.0000x reference)
//
#include <hip/hip_runtime.h>

#define BATCH 16384
#define N_NEG 10
#define N_DIM 128

__device__ __forceinline__ float log_sigmoid(float x) {
    // stable: min(x,0) - log1p(exp(-|x|))
    return fminf(x, 0.0f) - log1pf(__expf(-fabsf(x)));
}

__global__ __launch_bounds__(256) void all2vec_kernel(
    const int*   __restrict__ pos_v,
    const int*   __restrict__ pos_u,
    const int*   __restrict__ neg,
    const float* __restrict__ weights,
    const float* __restrict__ emb,
    const float* __restrict__ emb_ctx,
    float*       __restrict__ out)
{
    const int wave = threadIdx.x >> 6;   // 4 waves per block
    const int lane = threadIdx.x & 63;
    const int b = blockIdx.x * 4 + wave; // one batch element per wave
    if (b >= BATCH) return;

    const float2* e2 = (const float2*)emb;      // row stride = 64 float2
    const float2* c2 = (const float2*)emb_ctx;

    const long long iv = pos_v[b];
    const long long iu = pos_u[b];

    // emb_v row, held in registers (reused by all 12 dots)
    const float2 v = e2[iv * 64 + lane];

    float acc[12];
    {
        const float2 a = e2[iu * 64 + lane];   // emb[pos_u]
        acc[0] = a.x * v.x + a.y * v.y;
        const float2 c = c2[iu * 64 + lane];   // emb_ctx[pos_u]
        acc[1] = c.x * v.x + c.y * v.y;
    }
#pragma unroll
    for (int k = 0; k < N_NEG; ++k) {
        const long long nk = neg[b * N_NEG + k];
        const float2 n = c2[nk * 64 + lane];   // emb_ctx[neg[b,k]]
        acc[2 + k] = n.x * v.x + n.y * v.y;
    }

    // wave-wide reduction of all 12 partial dots (wave = 64 lanes)
#pragma unroll
    for (int j = 0; j < 12; ++j) {
#pragma unroll
        for (int off = 32; off > 0; off >>= 1)
            acc[j] += __shfl_down(acc[j], off, 64);
    }

    if (lane == 0) {
        const float w = weights[b];
        float negsum = 0.0f;
#pragma unroll
        for (int k = 0; k < N_NEG; ++k)
            negsum += log_sigmoid(-acc[2 + k]);
        out[b]         = w * (-log_sigmoid(acc[0]) - negsum);  // score_1
        out[BATCH + b] = w * (-log_sigmoid(acc[1]) - negsum);  // score_2
    }
}

extern "C" void kernel_launch(void* const* d_in, const int* in_sizes, int n_in,
                              void* d_out, int out_size, void* d_ws, size_t ws_size,
                              hipStream_t stream) {
    const int*   pos_v   = (const int*)d_in[0];
    const int*   pos_u   = (const int*)d_in[1];
    const int*   neg     = (const int*)d_in[2];
    const float* weights = (const float*)d_in[3];
    const float* emb     = (const float*)d_in[4];
    const float* emb_ctx = (const float*)d_in[5];
    float*       out     = (float*)d_out;

    const int waves_total = BATCH;           // one wave per batch element
    const int blocks = waves_total / 4;      // 4 waves (256 threads) per block
    all2vec_kernel<<<blocks, 256, 0, stream>>>(pos_v, pos_u, neg, weights,
                                               emb, emb_ctx, out);
}

// Round 2
// 774.387 us; speedup vs baseline: 1.0003x; 1.0003x over previous
//
#include <hip/hip_runtime.h>

#define BATCH 16384
#define N_NEG 10
#define N_DIM 128

__device__ __forceinline__ float log_sigmoid(float x) {
    // stable: min(x,0) - log1p(exp(-|x|))
    return fminf(x, 0.0f) - log1pf(__expf(-fabsf(x)));
}

// One 32-lane half-wave per batch element: lane loads float4 (16 B),
// 32 lanes * 16 B = one 512 B embedding row per load instruction.
__global__ __launch_bounds__(256) void all2vec_kernel(
    const int*   __restrict__ pos_v,
    const int*   __restrict__ pos_u,
    const int*   __restrict__ neg,
    const float* __restrict__ weights,
    const float* __restrict__ emb,
    const float* __restrict__ emb_ctx,
    float*       __restrict__ out)
{
    const int lane = threadIdx.x & 63;
    const int waveInBlock = threadIdx.x >> 6;      // 4 waves / block
    const int half = lane >> 5;                    // which 32-lane half
    const int sub  = lane & 31;                    // lane within half
    const int wgid = blockIdx.x * 4 + waveInBlock; // global wave id
    const int b    = wgid * 2 + half;              // batch element per half-wave

    const float4* e4 = (const float4*)emb;      // 32 float4 per 128-f row
    const float4* c4 = (const float4*)emb_ctx;

    // indices (wave-uniform per half; broadcast loads)
    const long long iv = pos_v[b];
    const long long iu = pos_u[b];
    int nidx[N_NEG];
#pragma unroll
    for (int k = 0; k < N_NEG; ++k) nidx[k] = neg[b * N_NEG + k];

    // issue all 13 row loads back-to-back (independent -> max MLP)
    const float4 v  = e4[iv * 32 + sub];
    const float4 ru = e4[iu * 32 + sub];
    const float4 rc = c4[iu * 32 + sub];
    float4 rn[N_NEG];
#pragma unroll
    for (int k = 0; k < N_NEG; ++k)
        rn[k] = c4[(long long)nidx[k] * 32 + sub];

    float acc[12];
    acc[0] = ru.x * v.x + ru.y * v.y + ru.z * v.z + ru.w * v.w;
    acc[1] = rc.x * v.x + rc.y * v.y + rc.z * v.z + rc.w * v.w;
#pragma unroll
    for (int k = 0; k < N_NEG; ++k)
        acc[2 + k] = rn[k].x * v.x + rn[k].y * v.y + rn[k].z * v.z + rn[k].w * v.w;

    // butterfly reduction within each 32-lane half (xor masks < 32 stay in-half)
#pragma unroll
    for (int j = 0; j < 12; ++j) {
#pragma unroll
        for (int m = 16; m > 0; m >>= 1)
            acc[j] += __shfl_xor(acc[j], m, 64);
    }

    if (sub == 0) {
        const float w = weights[b];
        float negsum = 0.0f;
#pragma unroll
        for (int k = 0; k < N_NEG; ++k)
            negsum += log_sigmoid(-acc[2 + k]);
        out[b]         = w * (-log_sigmoid(acc[0]) - negsum);  // score_1
        out[BATCH + b] = w * (-log_sigmoid(acc[1]) - negsum);  // score_2
    }
}

extern "C" void kernel_launch(void* const* d_in, const int* in_sizes, int n_in,
                              void* d_out, int out_size, void* d_ws, size_t ws_size,
                              hipStream_t stream) {
    const int*   pos_v   = (const int*)d_in[0];
    const int*   pos_u   = (const int*)d_in[1];
    const int*   neg     = (const int*)d_in[2];
    const float* weights = (const float*)d_in[3];
    const float* emb     = (const float*)d_in[4];
    const float* emb_ctx = (const float*)d_in[5];
    float*       out     = (float*)d_out;

    const int waves_total = BATCH / 2;        // 2 batch elements per wave
    const int blocks = waves_total / 4;       // 4 waves (256 thr) per block -> 2048
    all2vec_kernel<<<blocks, 256, 0, stream>>>(pos_v, pos_u, neg, weights,
                                               emb, emb_ctx, out);
}